// Round 5
// baseline (2098.743 us; speedup 1.0000x reference)
//
#include <hip/hip_runtime.h>
#include <stdint.h>

#define GLOBAL_AS __attribute__((address_space(1)))
#define LDS_AS    __attribute__((address_space(3)))

typedef _Float16 f16;
typedef _Float16 half8 __attribute__((ext_vector_type(8)));
typedef float    f32x4 __attribute__((ext_vector_type(4)));

constexpr int B_  = 16;
constexpr int T_  = 2048;
constexpr int IN_ = 65;
constexpr int HID = 64;
constexpr int G4  = 256;      // 4*HID
constexpr int FW  = 72;       // padded frame width (25*72 = 1800)
constexpr int KP  = 1824;     // padded K for layer0 (57*32)
constexpr int KC0 = KP / 32;  // 57
constexpr int RING = 512;     // h handoff ring depth (steps); back-pressure margin 256

// ---- workspace layout (bytes) ----
constexpr size_t OFF_XF   = 0;                          // [B][T][FW] f16
constexpr size_t SZ_XF    = (size_t)B_ * T_ * FW * 2;   // 4,718,592
constexpr size_t OFF_WP0  = OFF_XF + SZ_XF;             // [KC0][16][64][8] f16
constexpr size_t SZ_WP0   = (size_t)KC0 * 16 * 64 * 8 * 2;
constexpr size_t OFF_WHHF = OFF_WP0 + SZ_WP0;           // 3 x r-layout frags
constexpr size_t SZ_WHHF1 = (size_t)16 * 2 * 64 * 8 * 2;
constexpr size_t OFF_WIHR = OFF_WHHF + 3 * SZ_WHHF1;    // 2 x r-layout frags (Wih1, Wih2)
constexpr size_t SZ_WIHR1 = (size_t)16 * 2 * 64 * 8 * 2;
constexpr size_t OFF_BC   = OFF_WIHR + 2 * SZ_WIHR1;    // 3 x [256] f32
constexpr size_t OFF_PRE  = ((OFF_BC + 3 * 256 * 4 + 1023) / 1024) * 1024;  // [t][b][j][q] f32, layer 0 only
constexpr size_t SZ_PRE   = (size_t)T_ * B_ * G4 * 4;   // 33,554,432
constexpr size_t OFF_H2   = OFF_PRE + SZ_PRE;           // [B][T][HID] f16 (final layer h only)
constexpr size_t SZ_H     = (size_t)B_ * T_ * HID * 2;  // 4,194,304
constexpr size_t OFF_HX   = OFF_H2 + SZ_H;              // h handoff: [2 layers][RING][4 quads][4 b][64 j] f16
constexpr size_t SZ_HX    = (size_t)2 * RING * 4 * 512; // 2,097,152
constexpr size_t OFF_FLG  = OFF_HX + SZ_HX;             // u32 flags: [0..7] done(L*4+q), [8..19] prog
constexpr size_t SZ_FLG   = 128;

__device__ __forceinline__ void async_copy16(const void* g, void* l) {
  __builtin_amdgcn_global_load_lds((const GLOBAL_AS void*)g, (LDS_AS void*)l, 16, 0, 0);
}

// within-row byte offset for pre[t][b][g] (plain): g=(q*64+j) -> j*16 + q*4
__device__ __forceinline__ int pre_col_byte(int g) {
  int j = g & 63, q = g >> 6;
  return (j << 4) | (q << 2);
}

__device__ __forceinline__ float fsig(float x) {
  return __builtin_amdgcn_rcpf(1.f + __builtin_amdgcn_exp2f(-1.4426950408889634f * x));
}
__device__ __forceinline__ float ftanh(float x) {
  return 1.f - 2.f * __builtin_amdgcn_rcpf(1.f + __builtin_amdgcn_exp2f(2.8853900817779268f * x));
}

// ---- device-coherent (cross-XCD) access helpers: sc0 sc1 = bypass L1/L2, MALL-visible ----
__device__ __forceinline__ unsigned flagLoad(const unsigned* p) {
  unsigned v;
  asm volatile("global_load_dword %0, %1, off sc0 sc1\n\ts_waitcnt vmcnt(0)"
               : "=v"(v) : "v"((unsigned long long)(uintptr_t)p) : "memory");
  return v;
}
__device__ __forceinline__ void flagStore(unsigned* p, unsigned v) {
  asm volatile("global_store_dword %0, %1, off sc0 sc1"
               :: "v"((unsigned long long)(uintptr_t)p), "v"(v) : "memory");
}
__device__ __forceinline__ void xFragLoad(unsigned long long a, half8& x0, half8& x1) {
  asm volatile("global_load_dwordx4 %0, %2, off sc0 sc1\n\t"
               "global_load_dwordx4 %1, %2, off offset:64 sc0 sc1"
               : "=v"(x0), "=v"(x1) : "v"(a) : "memory");
}
__device__ __forceinline__ void hPairStore(unsigned long long a, unsigned v) {
  asm volatile("global_store_dword %0, %1, off sc0 sc1"
               :: "v"(a), "v"(v) : "memory");
}

// ================= pack kernel =================
__global__ void pack_kernel(const float* __restrict__ in0, const float* __restrict__ Wih0,
                            const float* __restrict__ Whh0, const float* __restrict__ bih0, const float* __restrict__ bhh0,
                            const float* __restrict__ Wih1, const float* __restrict__ Whh1, const float* __restrict__ bih1, const float* __restrict__ bhh1,
                            const float* __restrict__ Wih2, const float* __restrict__ Whh2, const float* __restrict__ bih2, const float* __restrict__ bhh2,
                            f16* __restrict__ xf, f16* __restrict__ wp0,
                            f16* __restrict__ whhf, f16* __restrict__ wihr, float* __restrict__ bc)
{
  const int stride = gridDim.x * blockDim.x;
  const int tid0 = blockIdx.x * blockDim.x + threadIdx.x;

  // xf: [B][T][FW], zero-pad f >= 65
  const int NX = B_ * T_ * FW;
  for (int i = tid0; i < NX; i += stride) {
    int f = i % FW; int bt = i / FW;
    float v = (f < IN_) ? in0[(size_t)bt * IN_ + f] : 0.f;
    xf[i] = (f16)v;
  }
  // wp0: [kc][nt][lane][8] ; k' = kc*32 + (l>>4)*8 + j ; g = nt*16 + (l&15)
  const int NW0 = KC0 * 16 * 64 * 8;
  for (int i = tid0; i < NW0; i += stride) {
    int j = i & 7, l = (i >> 3) & 63, nt = (i >> 9) & 15, kc = i >> 13;
    int kp = kc * 32 + ((l >> 4) * 8 + j);
    int g  = nt * 16 + (l & 15);
    int d = kp / FW, f = kp % FW;
    float v = (kp < 1800 && f < IN_) ? Wih0[(size_t)g * 1625 + d * IN_ + f] : 0.f;
    wp0[i] = (f16)v;
  }
  // whhf (r-layout): per layer, frag tt = wv*4+u, kf:
  //   g = u*64 + wv*16 + (l&15) ; k = kf*32 + (l>>4)*8 + e
  const float* whhs[3] = {Whh0, Whh1, Whh2};
  for (int i = tid0; i < 3 * 16384; i += stride) {
    int L = i >> 14, r = i & 16383;
    int e = r & 7, l = (r >> 3) & 63, kf = (r >> 9) & 1, tt = (r >> 10) & 15;
    int wv = tt >> 2, u = tt & 3;
    int g = u * 64 + wv * 16 + (l & 15);
    int k = kf * 32 + ((l >> 4) * 8) + e;
    whhf[i] = (f16)whhs[L][g * 64 + k];
  }
  // wihr (r-layout, same formula) from Wih1/Wih2 (both [256][64])
  const float* wihs[2] = {Wih1, Wih2};
  for (int i = tid0; i < 2 * 16384; i += stride) {
    int L = i >> 14, r = i & 16383;
    int e = r & 7, l = (r >> 3) & 63, kf = (r >> 9) & 1, tt = (r >> 10) & 15;
    int wv = tt >> 2, u = tt & 3;
    int g = u * 64 + wv * 16 + (l & 15);
    int k = kf * 32 + ((l >> 4) * 8) + e;
    wihr[i] = (f16)wihs[L][g * 64 + k];
  }
  // combined biases
  const float* bis[3] = {bih0, bih1, bih2};
  const float* bhs[3] = {bhh0, bhh1, bhh2};
  for (int i = tid0; i < 3 * 256; i += stride) {
    int L = i >> 8, g = i & 255;
    bc[i] = bis[L][g] + bhs[L][g];
  }
}

// ================= layer-0 windowed GEMM =================
// grid (32, 16): x = t-tile (64 rows), y = batch. 256 threads = 4 waves.
__global__ __launch_bounds__(256) void gemm0_kernel(const f16* __restrict__ xf, const f16* __restrict__ wp0,
                                                    const float* __restrict__ bc0, float* __restrict__ pre)
{
  __shared__ __align__(16) f16 frames[90 * FW];   // 12,960 B
  __shared__ __align__(16) f16 bbuf[16 * 64 * 8]; // 16,384 B
  const int tid = threadIdx.x, l = tid & 63, w = tid >> 6;
  const int b = blockIdx.y, t0 = blockIdx.x * 64;

  // zero frames (covers t-edge padding and the k'>=1800 tail rows)
  for (int c = tid; c < 810; c += 256) *(f32x4*)(&frames[c * 8]) = (f32x4)0.f;
  __syncthreads();

  // stage valid frame range [s0, s1) of this batch
  {
    const int st = t0 - 12;
    const int s0 = st < 0 ? 0 : st;
    const int s1 = (t0 + 78) < T_ ? (t0 + 78) : T_;
    const int dstrow = s0 - st;
    const int nchunk = (s1 - s0) * 9;  // 16B chunks (144 B/row)
    const f16* gsrc = xf + ((size_t)b * T_ + s0) * FW;
    for (int base = 0; base < 810; base += 256) {
      int idx = base + w * 64 + l;
      if (idx < nchunk) {
        char* ldsb = (char*)frames + dstrow * 144 + (base + w * 64) * 16;
        async_copy16((const char*)gsrc + (size_t)(base + w * 64) * 16 + l * 16, ldsb);
      }
    }
  }

  f32x4 acc[16];
#pragma unroll
  for (int i = 0; i < 16; ++i) acc[i] = (f32x4)0.f;

  for (int kc = 0; kc < KC0; ++kc) {
    __syncthreads();  // drains previous loads/reads; protects bbuf
    const f16* wsrc = wp0 + (size_t)kc * 8192;
#pragma unroll
    for (int i = 0; i < 4; ++i) {
      char* ldsb = (char*)bbuf + (i * 256 + w * 64) * 16;
      async_copy16((const char*)wsrc + (size_t)(i * 256 + w * 64 + l) * 16, ldsb);
    }
    __syncthreads();  // vmcnt(0) drain -> bbuf ready

    int kp0 = kc * 32 + ((l >> 4) * 8);
    int d = kp0 / FW, f = kp0 % FW;
    int r = w * 16 + (l & 15);
    half8 af = *(const half8*)(&frames[(r + d) * FW + f]);
#pragma unroll
    for (int nt = 0; nt < 16; ++nt) {
      half8 bf = *(const half8*)(&bbuf[(nt * 64 + l) * 8]);
      acc[nt] = __builtin_amdgcn_mfma_f32_16x16x32_f16(af, bf, acc[nt], 0, 0, 0);
    }
  }

  // epilogue: bias + plain [t][b][j][q] store
  const int n_ = l & 15, grp = l >> 4;
#pragma unroll
  for (int nt = 0; nt < 16; ++nt) {
    int g = nt * 16 + n_;
    float bias = bc0[g];
    int colByte = pre_col_byte(g);
#pragma unroll
    for (int rr = 0; rr < 4; ++rr) {
      int t = t0 + w * 16 + grp * 4 + rr;
      *(float*)((char*)pre + (size_t)t * 16384 + (size_t)b * 1024 + colByte) = acc[nt][rr] + bias;
    }
  }
}

// ================= layer-split LSTM recurrence =================
// grid = dim3(4 quads, 3 layers) x 256 threads (4 waves) -> 12 CUs.
// Each block runs ONE layer for 4 batches, self-timed; cross-layer handoff via
// a RING-slot hx buffer in MALL (sc0/sc1 device-coherent accesses) + done-flags
// (every 4 steps, published AFTER an in-pipeline vmcnt(0) so flag implies data).
// Consumers prefetch x[t+1] one step ahead; progress flags back-pressure the
// producer (margin 256 < RING=512; lag chain makes deadlock impossible).
__global__ __launch_bounds__(256) void rl_kernel(const float* __restrict__ pre,
                                                 const f16* __restrict__ whhf,
                                                 const f16* __restrict__ wihr,
                                                 const float* __restrict__ bc,
                                                 char* __restrict__ hx,
                                                 unsigned* __restrict__ flags,
                                                 f16* __restrict__ h2out)
{
  __shared__ __align__(16) char hbuf[2 * 640];  // own-h ping-pong, 4 b x 160 B
  const int tid = threadIdx.x, l = tid & 63, wv = tid >> 6;
  const int q = blockIdx.x, L = blockIdx.y;
  const int n_ = l & 15, grp = l >> 4;
  const int j = wv * 16 + n_;       // hidden index this lane updates
  const int bglob = q * 4 + grp;    // batch this lane updates
  const int arow = n_ >> 2;         // A-frag source batch (replicated rows)

  // recurrent (Whh) fragments, r-layout
  half8 bfh[4][2];
  const f16* wh = whhf + (size_t)L * 16384;
#pragma unroll
  for (int u = 0; u < 4; ++u)
#pragma unroll
    for (int kf = 0; kf < 2; ++kf)
      bfh[u][kf] = *(const half8*)(wh + (((wv * 4 + u) * 2 + kf) << 9) + (l << 3));

  // input (Wih) fragments + bias-as-C-in for layers 1,2
  half8 bfx[4][2];
  f32x4 cin[4];
  if (L > 0) {
    const f16* wx = wihr + (size_t)(L - 1) * 16384;
#pragma unroll
    for (int u = 0; u < 4; ++u) {
#pragma unroll
      for (int kf = 0; kf < 2; ++kf)
        bfx[u][kf] = *(const half8*)(wx + (((wv * 4 + u) * 2 + kf) << 9) + (l << 3));
      cin[u] = (f32x4)(bc[L * 256 + u * 64 + j]);
    }
  } else {
#pragma unroll
    for (int u = 0; u < 4; ++u) cin[u] = (f32x4)0.f;
  }

  if (tid < 80) *(f32x4*)(hbuf + tid * 16) = (f32x4)0.f;
  float c = 0.f;

  // parity-selected own-h pointers: step t writes slot t&1, reads slot (t-1)&1
  const char* ownRd0 = hbuf + 640 + arow * 160 + grp * 16;  // SP=0 reads slot 1
  const char* ownRd1 = hbuf +   0 + arow * 160 + grp * 16;  // SP=1 reads slot 0
  char* wr0 = hbuf +   0 + grp * 160 + j * 2;
  char* wr1 = hbuf + 640 + grp * 160 + j * 2;

  // handoff addresses
  const unsigned long long inB =
      (unsigned long long)(uintptr_t)(hx + (size_t)(L > 0 ? L - 1 : 0) * RING * 2048 + q * 512 + arow * 128 + grp * 16);
  const unsigned long long outB =
      (unsigned long long)(uintptr_t)(hx + (size_t)L * RING * 2048 + q * 512 + grp * 128 + (size_t)(j & ~1) * 2);
  unsigned* doneIn  = flags + (L > 0 ? L - 1 : 0) * 4 + q;  // producer's completion (valid L>0)
  unsigned* doneOut = flags + L * 4 + q;                    // my completion (valid L<2)
  unsigned* progIn  = flags + 8 + L * 4 + q;                // my progress (published if L>0)
  unsigned* progOut = flags + 8 + (L + 1) * 4 + q;          // my consumer's progress (valid L<2)

  // layer-0 pre register ring (depth 3)
  f32x4 P0 = (f32x4)0.f, P1 = (f32x4)0.f, P2 = (f32x4)0.f, P3 = (f32x4)0.f;
  const GLOBAL_AS char* preP =
      (const GLOBAL_AS char*)(uintptr_t)((const char*)pre + (size_t)bglob * 1024 + (size_t)j * 16);
  // consumer x fragments, double-buffered
  half8 xA0, xA1, xB0, xB1;
  unsigned lastF = 0, lastP = 0;

  if (L == 0) {
    P0 = *(const GLOBAL_AS f32x4*)(preP);
    P1 = *(const GLOBAL_AS f32x4*)(preP + 16384);
    P2 = *(const GLOBAL_AS f32x4*)(preP + 32768);
    preP += 3 * 16384;
  } else {
    while (lastF < 1u) { __builtin_amdgcn_s_sleep(2); lastF = flagLoad(doneIn); }
    xFragLoad(inB, xA0, xA1);
  }
  GLOBAL_AS f16* h2p = (GLOBAL_AS f16*)(uintptr_t)(h2out + (size_t)bglob * T_ * HID + j);

#define RLSTEP(T_IDX, PU_, PLD_, XU0_, XU1_, XL0_, XL1_, SP_)                                  \
  {                                                                                             \
    const int t = (T_IDX);                                                                      \
    asm volatile("s_waitcnt lgkmcnt(0)" ::: "memory");                                          \
    __builtin_amdgcn_s_barrier();                                                               \
    asm volatile("s_waitcnt vmcnt(0)" ::: "memory");                                            \
    __builtin_amdgcn_sched_barrier(0);                                                          \
    /* publish flags at step start: all prior publishes retired by the vmcnt(0) above */        \
    if ((t & 3) == 0 && t > 0 && tid == 0) {                                                    \
      if (L < 2) flagStore(doneOut, (unsigned)t);                                               \
      if (L > 0) flagStore(progIn, (unsigned)t);                                                \
    }                                                                                           \
    /* producer back-pressure: slot t&(RING-1) must be past consumer by < RING */               \
    if (L < 2 && (t & 255) == 0 && t >= RING) {                                                 \
      unsigned need = (unsigned)(t - 256);                                                      \
      while (lastP < need) { __builtin_amdgcn_s_sleep(4); lastP = flagLoad(progOut); }          \
    }                                                                                           \
    const char* Hc = (SP_) ? ownRd1 : ownRd0;                                                   \
    half8 a0 = *(const half8*)(Hc);                                                             \
    half8 a1 = *(const half8*)(Hc + 64);                                                        \
    f32x4 acc[4];                                                                               \
    if (L > 0) {                                                                                \
      _Pragma("unroll")                                                                         \
      for (int u = 0; u < 4; ++u) {                                                             \
        acc[u] = __builtin_amdgcn_mfma_f32_16x16x32_f16(XU0_, bfx[u][0], cin[u], 0, 0, 0);      \
        acc[u] = __builtin_amdgcn_mfma_f32_16x16x32_f16(XU1_, bfx[u][1], acc[u], 0, 0, 0);      \
        acc[u] = __builtin_amdgcn_mfma_f32_16x16x32_f16(a0, bfh[u][0], acc[u], 0, 0, 0);        \
        acc[u] = __builtin_amdgcn_mfma_f32_16x16x32_f16(a1, bfh[u][1], acc[u], 0, 0, 0);        \
      }                                                                                         \
    } else {                                                                                    \
      _Pragma("unroll")                                                                         \
      for (int u = 0; u < 4; ++u) {                                                             \
        acc[u] = __builtin_amdgcn_mfma_f32_16x16x32_f16(a0, bfh[u][0], cin[u], 0, 0, 0);        \
        acc[u] = __builtin_amdgcn_mfma_f32_16x16x32_f16(a1, bfh[u][1], acc[u], 0, 0, 0);        \
      }                                                                                         \
    }                                                                                           \
    /* prefetch next input while MFMAs drain */                                                 \
    if (L > 0) {                                                                                \
      if (t + 1 < T_) {                                                                         \
        unsigned need = (unsigned)(t + 2);                                                      \
        while (lastF < need) { __builtin_amdgcn_s_sleep(2); lastF = flagLoad(doneIn); }         \
        xFragLoad(inB + (unsigned long long)((t + 1) & (RING - 1)) * 2048, XL0_, XL1_);         \
      }                                                                                         \
    } else {                                                                                    \
      if (t + 3 < T_) { PLD_ = *(const GLOBAL_AS f32x4*)(preP); preP += 16384; }                \
    }                                                                                           \
    float iv, fv, gv, ov;                                                                       \
    if (L == 0) {                                                                               \
      iv = acc[0][0] + PU_.x; fv = acc[1][0] + PU_.y;                                           \
      gv = acc[2][0] + PU_.z; ov = acc[3][0] + PU_.w;                                           \
    } else {                                                                                    \
      iv = acc[0][0]; fv = acc[1][0]; gv = acc[2][0]; ov = acc[3][0];                           \
    }                                                                                           \
    c = fsig(fv) * c + fsig(iv) * ftanh(gv);                                                    \
    float hv = fsig(ov) * ftanh(c);                                                             \
    f16 h16v = (f16)hv;                                                                         \
    *(f16*)((SP_) ? wr1 : wr0) = h16v;                                                          \
    if (L < 2) {                                                                                \
      unsigned hb = (unsigned)__builtin_bit_cast(unsigned short, h16v);                         \
      unsigned ob = (unsigned)__shfl_xor((int)hb, 1, 64);                                       \
      if ((n_ & 1) == 0)                                                                        \
        hPairStore(outB + (unsigned long long)(t & (RING - 1)) * 2048, hb | (ob << 16));        \
    } else {                                                                                    \
      *h2p = h16v; h2p += HID;                                                                  \
    }                                                                                           \
  }

  for (int t4 = 0; t4 < T_; t4 += 4) {
    RLSTEP(t4 + 0, P0, P3, xA0, xA1, xB0, xB1, 0)
    RLSTEP(t4 + 1, P1, P0, xB0, xB1, xA0, xA1, 1)
    RLSTEP(t4 + 2, P2, P1, xA0, xA1, xB0, xB1, 0)
    RLSTEP(t4 + 3, P3, P2, xB0, xB1, xA0, xA1, 1)
  }
#undef RLSTEP

  // epilogue: final completion flag (consumers poll up to done >= T_)
  asm volatile("s_waitcnt vmcnt(0) lgkmcnt(0)" ::: "memory");
  if (L < 2 && tid == 0) flagStore(doneOut, (unsigned)T_);
}

// ================= final projection =================
__global__ __launch_bounds__(256) void fin_kernel(const f16* __restrict__ h2, const float* __restrict__ Wout,
                                                  const float* __restrict__ bout, float* __restrict__ out)
{
  __shared__ float wl[64];
  const int tid = threadIdx.x;
  if (tid < 64) wl[tid] = Wout[tid];
  __syncthreads();
  const int idx = blockIdx.x * 256 + tid;  // = b*T + t
  const f16* hr = h2 + (size_t)idx * HID;
  float acc = bout[0];
#pragma unroll
  for (int i = 0; i < 64; i += 8) {
    half8 hv = *(const half8*)(hr + i);
#pragma unroll
    for (int k = 0; k < 8; ++k) {
      float h = (float)hv[k];
      h = fmaxf(h, 0.f);
      acc += h * wl[i + k];
    }
  }
  out[idx] = fsig(acc);
}

// ================= launcher =================
extern "C" void kernel_launch(void* const* d_in, const int* in_sizes, int n_in,
                              void* d_out, int out_size, void* d_ws, size_t ws_size,
                              hipStream_t stream)
{
  (void)in_sizes; (void)n_in; (void)out_size; (void)ws_size;
  const float* in0  = (const float*)d_in[0];
  const float* Wih0 = (const float*)d_in[1];
  const float* Whh0 = (const float*)d_in[2];
  const float* bih0 = (const float*)d_in[3];
  const float* bhh0 = (const float*)d_in[4];
  const float* Wih1 = (const float*)d_in[5];
  const float* Whh1 = (const float*)d_in[6];
  const float* bih1 = (const float*)d_in[7];
  const float* bhh1 = (const float*)d_in[8];
  const float* Wih2 = (const float*)d_in[9];
  const float* Whh2 = (const float*)d_in[10];
  const float* bih2 = (const float*)d_in[11];
  const float* bhh2 = (const float*)d_in[12];
  const float* Wout = (const float*)d_in[13];
  const float* bout = (const float*)d_in[14];
  float* out = (float*)d_out;

  char* ws = (char*)d_ws;
  f16*   xf   = (f16*)(ws + OFF_XF);
  f16*   wp0  = (f16*)(ws + OFF_WP0);
  f16*   whhf = (f16*)(ws + OFF_WHHF);
  f16*   wihr = (f16*)(ws + OFF_WIHR);
  float* bc   = (float*)(ws + OFF_BC);
  float* pre  = (float*)(ws + OFF_PRE);
  f16*   h2   = (f16*)(ws + OFF_H2);
  char*  hx   = ws + OFF_HX;
  unsigned* flags = (unsigned*)(ws + OFF_FLG);

  pack_kernel<<<256, 256, 0, stream>>>(in0, Wih0, Whh0, bih0, bhh0,
                                       Wih1, Whh1, bih1, bhh1,
                                       Wih2, Whh2, bih2, bhh2,
                                       xf, wp0, whhf, wihr, bc);
  gemm0_kernel<<<dim3(32, 16), 256, 0, stream>>>(xf, wp0, bc, pre);
  hipMemsetAsync(ws + OFF_FLG, 0, SZ_FLG, stream);
  rl_kernel<<<dim3(4, 3), 256, 0, stream>>>(pre, whhf, wihr, bc, hx, flags, h2);
  fin_kernel<<<128, 256, 0, stream>>>(h2, Wout, bout, out);
}

// Round 6
// 1322.721 us; speedup vs baseline: 1.5867x; 1.5867x over previous
//
#include <hip/hip_runtime.h>
#include <stdint.h>

#define GLOBAL_AS __attribute__((address_space(1)))
#define LDS_AS    __attribute__((address_space(3)))

typedef _Float16 f16;
typedef _Float16 half8 __attribute__((ext_vector_type(8)));
typedef float    f32x4 __attribute__((ext_vector_type(4)));

constexpr int B_  = 16;
constexpr int T_  = 2048;
constexpr int IN_ = 65;
constexpr int HID = 64;
constexpr int G4  = 256;      // 4*HID
constexpr int FW  = 72;       // padded frame width (25*72 = 1800)
constexpr int KP  = 1824;     // padded K for layer0 (57*32)
constexpr int KC0 = KP / 32;  // 57

// ---- workspace layout (bytes) ----
constexpr size_t OFF_XF   = 0;                          // [B][T][FW] f16
constexpr size_t SZ_XF    = (size_t)B_ * T_ * FW * 2;   // 4,718,592
constexpr size_t OFF_WP0  = OFF_XF + SZ_XF;             // [KC0][16][64][8] f16
constexpr size_t SZ_WP0   = (size_t)KC0 * 16 * 64 * 8 * 2;
constexpr size_t OFF_WHHF = OFF_WP0 + SZ_WP0;           // 3 x r-layout frags
constexpr size_t SZ_WHHF1 = (size_t)16 * 2 * 64 * 8 * 2;
constexpr size_t OFF_WIHR = OFF_WHHF + 3 * SZ_WHHF1;    // 2 x r-layout frags (Wih1, Wih2)
constexpr size_t SZ_WIHR1 = (size_t)16 * 2 * 64 * 8 * 2;
constexpr size_t OFF_BC   = OFF_WIHR + 2 * SZ_WIHR1;    // 3 x [256] f32
constexpr size_t OFF_PRE  = ((OFF_BC + 3 * 256 * 4 + 1023) / 1024) * 1024;  // [t][b][j][q] f32, layer 0 only
constexpr size_t SZ_PRE   = (size_t)T_ * B_ * G4 * 4;   // 33,554,432
constexpr size_t OFF_H2   = OFF_PRE + SZ_PRE;           // [B][T][HID] f16 (final layer h only)
constexpr size_t SZ_H     = (size_t)B_ * T_ * HID * 2;  // 4,194,304

__device__ __forceinline__ void async_copy16(const void* g, void* l) {
  __builtin_amdgcn_global_load_lds((const GLOBAL_AS void*)g, (LDS_AS void*)l, 16, 0, 0);
}

// within-row byte offset for pre[t][b][g] (plain): g=(q*64+j) -> j*16 + q*4
__device__ __forceinline__ int pre_col_byte(int g) {
  int j = g & 63, q = g >> 6;
  return (j << 4) | (q << 2);
}

__device__ __forceinline__ float fsig(float x) {
  return __builtin_amdgcn_rcpf(1.f + __builtin_amdgcn_exp2f(-1.4426950408889634f * x));
}
__device__ __forceinline__ float ftanh(float x) {
  return 1.f - 2.f * __builtin_amdgcn_rcpf(1.f + __builtin_amdgcn_exp2f(2.8853900817779268f * x));
}

// ================= pack kernel =================
__global__ void pack_kernel(const float* __restrict__ in0, const float* __restrict__ Wih0,
                            const float* __restrict__ Whh0, const float* __restrict__ bih0, const float* __restrict__ bhh0,
                            const float* __restrict__ Wih1, const float* __restrict__ Whh1, const float* __restrict__ bih1, const float* __restrict__ bhh1,
                            const float* __restrict__ Wih2, const float* __restrict__ Whh2, const float* __restrict__ bih2, const float* __restrict__ bhh2,
                            f16* __restrict__ xf, f16* __restrict__ wp0,
                            f16* __restrict__ whhf, f16* __restrict__ wihr, float* __restrict__ bc)
{
  const int stride = gridDim.x * blockDim.x;
  const int tid0 = blockIdx.x * blockDim.x + threadIdx.x;

  // xf: [B][T][FW], zero-pad f >= 65
  const int NX = B_ * T_ * FW;
  for (int i = tid0; i < NX; i += stride) {
    int f = i % FW; int bt = i / FW;
    float v = (f < IN_) ? in0[(size_t)bt * IN_ + f] : 0.f;
    xf[i] = (f16)v;
  }
  // wp0: [kc][nt][lane][8] ; k' = kc*32 + (l>>4)*8 + j ; g = nt*16 + (l&15)
  const int NW0 = KC0 * 16 * 64 * 8;
  for (int i = tid0; i < NW0; i += stride) {
    int j = i & 7, l = (i >> 3) & 63, nt = (i >> 9) & 15, kc = i >> 13;
    int kp = kc * 32 + ((l >> 4) * 8 + j);
    int g  = nt * 16 + (l & 15);
    int d = kp / FW, f = kp % FW;
    float v = (kp < 1800 && f < IN_) ? Wih0[(size_t)g * 1625 + d * IN_ + f] : 0.f;
    wp0[i] = (f16)v;
  }
  // whhf (r-layout): per layer, frag tt = jb*4+u, kf:
  //   g = u*64 + jb*16 + (l&15) ; k = kf*32 + (l>>4)*8 + e
  const float* whhs[3] = {Whh0, Whh1, Whh2};
  for (int i = tid0; i < 3 * 16384; i += stride) {
    int L = i >> 14, r = i & 16383;
    int e = r & 7, l = (r >> 3) & 63, kf = (r >> 9) & 1, tt = (r >> 10) & 15;
    int jb = tt >> 2, u = tt & 3;
    int g = u * 64 + jb * 16 + (l & 15);
    int k = kf * 32 + ((l >> 4) * 8) + e;
    whhf[i] = (f16)whhs[L][g * 64 + k];
  }
  // wihr (r-layout, same formula) from Wih1/Wih2 (both [256][64])
  const float* wihs[2] = {Wih1, Wih2};
  for (int i = tid0; i < 2 * 16384; i += stride) {
    int L = i >> 14, r = i & 16383;
    int e = r & 7, l = (r >> 3) & 63, kf = (r >> 9) & 1, tt = (r >> 10) & 15;
    int jb = tt >> 2, u = tt & 3;
    int g = u * 64 + jb * 16 + (l & 15);
    int k = kf * 32 + ((l >> 4) * 8) + e;
    wihr[i] = (f16)wihs[L][g * 64 + k];
  }
  // combined biases
  const float* bis[3] = {bih0, bih1, bih2};
  const float* bhs[3] = {bhh0, bhh1, bhh2};
  for (int i = tid0; i < 3 * 256; i += stride) {
    int L = i >> 8, g = i & 255;
    bc[i] = bis[L][g] + bhs[L][g];
  }
}

// ================= layer-0 windowed GEMM =================
// grid (32, 16): x = t-tile (64 rows), y = batch. 256 threads = 4 waves.
__global__ __launch_bounds__(256) void gemm0_kernel(const f16* __restrict__ xf, const f16* __restrict__ wp0,
                                                    const float* __restrict__ bc0, float* __restrict__ pre)
{
  __shared__ __align__(16) f16 frames[90 * FW];   // 12,960 B
  __shared__ __align__(16) f16 bbuf[16 * 64 * 8]; // 16,384 B
  const int tid = threadIdx.x, l = tid & 63, w = tid >> 6;
  const int b = blockIdx.y, t0 = blockIdx.x * 64;

  // zero frames (covers t-edge padding and the k'>=1800 tail rows)
  for (int c = tid; c < 810; c += 256) *(f32x4*)(&frames[c * 8]) = (f32x4)0.f;
  __syncthreads();

  // stage valid frame range [s0, s1) of this batch
  {
    const int st = t0 - 12;
    const int s0 = st < 0 ? 0 : st;
    const int s1 = (t0 + 78) < T_ ? (t0 + 78) : T_;
    const int dstrow = s0 - st;
    const int nchunk = (s1 - s0) * 9;  // 16B chunks (144 B/row)
    const f16* gsrc = xf + ((size_t)b * T_ + s0) * FW;
    for (int base = 0; base < 810; base += 256) {
      int idx = base + w * 64 + l;
      if (idx < nchunk) {
        char* ldsb = (char*)frames + dstrow * 144 + (base + w * 64) * 16;
        async_copy16((const char*)gsrc + (size_t)(base + w * 64) * 16 + l * 16, ldsb);
      }
    }
  }

  f32x4 acc[16];
#pragma unroll
  for (int i = 0; i < 16; ++i) acc[i] = (f32x4)0.f;

  for (int kc = 0; kc < KC0; ++kc) {
    __syncthreads();  // drains previous loads/reads; protects bbuf
    const f16* wsrc = wp0 + (size_t)kc * 8192;
#pragma unroll
    for (int i = 0; i < 4; ++i) {
      char* ldsb = (char*)bbuf + (i * 256 + w * 64) * 16;
      async_copy16((const char*)wsrc + (size_t)(i * 256 + w * 64 + l) * 16, ldsb);
    }
    __syncthreads();  // vmcnt(0) drain -> bbuf ready

    int kp0 = kc * 32 + ((l >> 4) * 8);
    int d = kp0 / FW, f = kp0 % FW;
    int r = w * 16 + (l & 15);
    half8 af = *(const half8*)(&frames[(r + d) * FW + f]);
#pragma unroll
    for (int nt = 0; nt < 16; ++nt) {
      half8 bf = *(const half8*)(&bbuf[(nt * 64 + l) * 8]);
      acc[nt] = __builtin_amdgcn_mfma_f32_16x16x32_f16(af, bf, acc[nt], 0, 0, 0);
    }
  }

  // epilogue: bias + plain [t][b][j][q] store
  const int n_ = l & 15, grp = l >> 4;
#pragma unroll
  for (int nt = 0; nt < 16; ++nt) {
    int g = nt * 16 + n_;
    float bias = bc0[g];
    int colByte = pre_col_byte(g);
#pragma unroll
    for (int rr = 0; rr < 4; ++rr) {
      int t = t0 + w * 16 + grp * 4 + rr;
      *(float*)((char*)pre + (size_t)t * 16384 + (size_t)b * 1024 + colByte) = acc[nt][rr] + bias;
    }
  }
}

// ================= fused 3-layer LSTM recurrence, 8 blocks x 6 waves =================
// Block handles 2 batches; wave w: layer L=w>>1, half wv=w&1. Lane (grp,n):
// batch b_loc=grp>>1, j=(2wv+(grp&1))*16+n. A replicated 8x (16 rows = 2b x 8);
// per wave 8 N-tiles (jb in {2wv,2wv+1} x u), lane picks its jb-acc with one
// cndmask per gate. ONE barrier/step, parity-selected LDS pointers, depth-3
// register pre-ring for L0, Wih folded into MFMAs for L1/L2.
__global__ __launch_bounds__(384, 2) void r6_kernel(const float* __restrict__ pre,
                                                    const f16* __restrict__ whhf,
                                                    const f16* __restrict__ wihr,
                                                    const float* __restrict__ bc,
                                                    f16* __restrict__ h2out)
{
  __shared__ __align__(16) char hring[6 * 256];   // [layer][slot][b_loc][64 k] f16
  const int tid = threadIdx.x, l = tid & 63, w = tid >> 6;
  const int L = w >> 1, wv = w & 1;
  const int n_ = l & 15, grp = l >> 4;
  const int jb_own = wv * 2 + (grp & 1);
  const int j  = jb_own * 16 + n_;   // hidden index this lane updates
  const int b_loc = grp >> 1;        // local batch this lane updates
  const int bglob = blockIdx.x * 2 + b_loc;
  const int arow = n_ >> 3;          // A-frag source batch (row n_, batch n_>>3)
  const bool selB = (grp & 1) != 0;  // lane uses jb = 2wv+1 accs

  // recurrent (Whh) fragments: tiles (jb = 2wv+ji, u), kf
  half8 bfh[2][4][2];
  const f16* wh = whhf + (size_t)L * 16384;
#pragma unroll
  for (int ji = 0; ji < 2; ++ji)
#pragma unroll
    for (int u = 0; u < 4; ++u)
#pragma unroll
      for (int kf = 0; kf < 2; ++kf) {
        int tt = (wv * 2 + ji) * 4 + u;
        bfh[ji][u][kf] = *(const half8*)(wh + (((tt * 2) + kf) << 9) + (l << 3));
      }

  // input (Wih) fragments for layers 1,2
  half8 bfx[2][4][2];
  if (L > 0) {
    const f16* wx = wihr + (size_t)(L - 1) * 16384;
#pragma unroll
    for (int ji = 0; ji < 2; ++ji)
#pragma unroll
      for (int u = 0; u < 4; ++u)
#pragma unroll
        for (int kf = 0; kf < 2; ++kf) {
          int tt = (wv * 2 + ji) * 4 + u;
          bfx[ji][u][kf] = *(const half8*)(wx + (((tt * 2) + kf) << 9) + (l << 3));
        }
  }

  float bi[4] = {0.f, 0.f, 0.f, 0.f};
  if (L > 0) {
#pragma unroll
    for (int u = 0; u < 4; ++u) bi[u] = bc[L * 256 + u * 64 + j];
  }

  // zero h rings (1536 B)
  if (tid < 96) *(f32x4*)(hring + tid * 16) = (f32x4)0.f;
  float c = 0.f;

  // parity-selected LDS pointers (t&1 = sp ^ (L&1))
  const int lp = L & 1;
  const int Lm1 = (L > 0) ? (L - 1) : 0;
  const char* ownRd0 = hring + (L * 2 + (1 ^ lp)) * 256 + arow * 128 + grp * 16;   // sp=0: slot (t-1)&1
  const char* ownRd1 = hring + (L * 2 + (0 ^ lp)) * 256 + arow * 128 + grp * 16;   // sp=1
  const char* inRd0  = hring + (Lm1 * 2 + (0 ^ lp)) * 256 + arow * 128 + grp * 16; // sp=0: slot t&1
  const char* inRd1  = hring + (Lm1 * 2 + (1 ^ lp)) * 256 + arow * 128 + grp * 16; // sp=1
  char* wr0 = hring + (L * 2 + (0 ^ lp)) * 256 + b_loc * 128 + j * 2;              // sp=0: slot t&1
  char* wr1 = hring + (L * 2 + (1 ^ lp)) * 256 + b_loc * 128 + j * 2;              // sp=1

  // register pre ring (L0 only), depth 3
  f32x4 P0 = (f32x4)0.f, P1 = (f32x4)0.f, P2 = (f32x4)0.f, P3 = (f32x4)0.f;
  const GLOBAL_AS char* preP =
      (const GLOBAL_AS char*)(uintptr_t)((const char*)pre + (size_t)bglob * 1024 + (size_t)j * 16);
  if (L == 0) {
    P0 = *(const GLOBAL_AS f32x4*)(preP);
    P1 = *(const GLOBAL_AS f32x4*)(preP + 16384);
    P2 = *(const GLOBAL_AS f32x4*)(preP + 32768);
    preP += 3 * 16384;
  }
  GLOBAL_AS f16* h2p = (GLOBAL_AS f16*)(uintptr_t)(h2out + (size_t)bglob * T_ * HID + j);

#define R6STEP(S_, PU_, PLD_, SP_)                                                             \
  {                                                                                            \
    asm volatile("s_waitcnt lgkmcnt(0)" ::: "memory");                                         \
    __builtin_amdgcn_s_barrier();                                                              \
    __builtin_amdgcn_sched_barrier(0);                                                         \
    const int t = (S_) - L;                                                                    \
    const bool act = (unsigned)t < (unsigned)T_;                                               \
    if (L == 0 && (t + 3) < T_) {                                                              \
      PLD_ = *(const GLOBAL_AS f32x4*)(preP);                                                  \
      preP += 16384;                                                                           \
    }                                                                                          \
    if (act) {                                                                                 \
      const char* Hc = (SP_) ? ownRd1 : ownRd0;                                                \
      half8 a0 = *(const half8*)(Hc);                                                          \
      half8 a1 = *(const half8*)(Hc + 64);                                                     \
      f32x4 aA[4], aB[4];                                                                      \
      if (L > 0) {                                                                             \
        const char* Xc = (SP_) ? inRd1 : inRd0;                                                \
        half8 x0 = *(const half8*)(Xc);                                                        \
        half8 x1 = *(const half8*)(Xc + 64);                                                   \
        _Pragma("unroll")                                                                      \
        for (int u = 0; u < 4; ++u) {                                                          \
          aA[u] = __builtin_amdgcn_mfma_f32_16x16x32_f16(x0, bfx[0][u][0], (f32x4)0.f, 0, 0, 0); \
          aA[u] = __builtin_amdgcn_mfma_f32_16x16x32_f16(x1, bfx[0][u][1], aA[u], 0, 0, 0);    \
          aA[u] = __builtin_amdgcn_mfma_f32_16x16x32_f16(a0, bfh[0][u][0], aA[u], 0, 0, 0);    \
          aA[u] = __builtin_amdgcn_mfma_f32_16x16x32_f16(a1, bfh[0][u][1], aA[u], 0, 0, 0);    \
          aB[u] = __builtin_amdgcn_mfma_f32_16x16x32_f16(x0, bfx[1][u][0], (f32x4)0.f, 0, 0, 0); \
          aB[u] = __builtin_amdgcn_mfma_f32_16x16x32_f16(x1, bfx[1][u][1], aB[u], 0, 0, 0);    \
          aB[u] = __builtin_amdgcn_mfma_f32_16x16x32_f16(a0, bfh[1][u][0], aB[u], 0, 0, 0);    \
          aB[u] = __builtin_amdgcn_mfma_f32_16x16x32_f16(a1, bfh[1][u][1], aB[u], 0, 0, 0);    \
        }                                                                                      \
      } else {                                                                                 \
        _Pragma("unroll")                                                                      \
        for (int u = 0; u < 4; ++u) {                                                          \
          aA[u] = __builtin_amdgcn_mfma_f32_16x16x32_f16(a0, bfh[0][u][0], (f32x4)0.f, 0, 0, 0); \
          aA[u] = __builtin_amdgcn_mfma_f32_16x16x32_f16(a1, bfh[0][u][1], aA[u], 0, 0, 0);    \
          aB[u] = __builtin_amdgcn_mfma_f32_16x16x32_f16(a0, bfh[1][u][0], (f32x4)0.f, 0, 0, 0); \
          aB[u] = __builtin_amdgcn_mfma_f32_16x16x32_f16(a1, bfh[1][u][1], aB[u], 0, 0, 0);    \
        }                                                                                      \
      }                                                                                        \
      float g0 = selB ? aB[0][0] : aA[0][0];                                                   \
      float g1 = selB ? aB[1][0] : aA[1][0];                                                   \
      float g2 = selB ? aB[2][0] : aA[2][0];                                                   \
      float g3 = selB ? aB[3][0] : aA[3][0];                                                   \
      float iv, fv, gv, ov;                                                                    \
      if (L == 0) {                                                                            \
        iv = g0 + PU_.x; fv = g1 + PU_.y; gv = g2 + PU_.z; ov = g3 + PU_.w;                    \
      } else {                                                                                 \
        iv = g0 + bi[0]; fv = g1 + bi[1]; gv = g2 + bi[2]; ov = g3 + bi[3];                    \
      }                                                                                        \
      c = fsig(fv) * c + fsig(iv) * ftanh(gv);                                                 \
      float hv = fsig(ov) * ftanh(c);                                                          \
      f16 h16v = (f16)hv;                                                                      \
      *(f16*)((SP_) ? wr1 : wr0) = h16v;                                                       \
      if (L == 2) { *h2p = h16v; h2p += HID; }                                                 \
    }                                                                                          \
  }

  // steps s = 0 .. 2051 (covers t up to 2047 for L=2 at s=2049)
  for (int s4 = 0; s4 < T_ + 4; s4 += 4) {
    R6STEP(s4 + 0, P0, P3, 0)
    R6STEP(s4 + 1, P1, P0, 1)
    R6STEP(s4 + 2, P2, P1, 0)
    R6STEP(s4 + 3, P3, P2, 1)
  }
#undef R6STEP
}

// ================= final projection =================
__global__ __launch_bounds__(256) void fin_kernel(const f16* __restrict__ h2, const float* __restrict__ Wout,
                                                  const float* __restrict__ bout, float* __restrict__ out)
{
  __shared__ float wl[64];
  const int tid = threadIdx.x;
  if (tid < 64) wl[tid] = Wout[tid];
  __syncthreads();
  const int idx = blockIdx.x * 256 + tid;  // = b*T + t
  const f16* hr = h2 + (size_t)idx * HID;
  float acc = bout[0];
#pragma unroll
  for (int i = 0; i < 64; i += 8) {
    half8 hv = *(const half8*)(hr + i);
#pragma unroll
    for (int k = 0; k < 8; ++k) {
      float h = (float)hv[k];
      h = fmaxf(h, 0.f);
      acc += h * wl[i + k];
    }
  }
  out[idx] = fsig(acc);
}

// ================= launcher =================
extern "C" void kernel_launch(void* const* d_in, const int* in_sizes, int n_in,
                              void* d_out, int out_size, void* d_ws, size_t ws_size,
                              hipStream_t stream)
{
  (void)in_sizes; (void)n_in; (void)out_size; (void)ws_size;
  const float* in0  = (const float*)d_in[0];
  const float* Wih0 = (const float*)d_in[1];
  const float* Whh0 = (const float*)d_in[2];
  const float* bih0 = (const float*)d_in[3];
  const float* bhh0 = (const float*)d_in[4];
  const float* Wih1 = (const float*)d_in[5];
  const float* Whh1 = (const float*)d_in[6];
  const float* bih1 = (const float*)d_in[7];
  const float* bhh1 = (const float*)d_in[8];
  const float* Wih2 = (const float*)d_in[9];
  const float* Whh2 = (const float*)d_in[10];
  const float* bih2 = (const float*)d_in[11];
  const float* bhh2 = (const float*)d_in[12];
  const float* Wout = (const float*)d_in[13];
  const float* bout = (const float*)d_in[14];
  float* out = (float*)d_out;

  char* ws = (char*)d_ws;
  f16*   xf   = (f16*)(ws + OFF_XF);
  f16*   wp0  = (f16*)(ws + OFF_WP0);
  f16*   whhf = (f16*)(ws + OFF_WHHF);
  f16*   wihr = (f16*)(ws + OFF_WIHR);
  float* bc   = (float*)(ws + OFF_BC);
  float* pre  = (float*)(ws + OFF_PRE);
  f16*   h2   = (f16*)(ws + OFF_H2);

  pack_kernel<<<256, 256, 0, stream>>>(in0, Wih0, Whh0, bih0, bhh0,
                                       Wih1, Whh1, bih1, bhh1,
                                       Wih2, Whh2, bih2, bhh2,
                                       xf, wp0, whhf, wihr, bc);
  gemm0_kernel<<<dim3(32, 16), 256, 0, stream>>>(xf, wp0, bc, pre);
  r6_kernel<<<8, 384, 0, stream>>>(pre, whhf, wihr, bc, h2);
  fin_kernel<<<128, 256, 0, stream>>>(h2, Wout, bout, out);
}

// Round 7
// 1322.278 us; speedup vs baseline: 1.5872x; 1.0003x over previous
//
#include <hip/hip_runtime.h>
#include <stdint.h>

#define GLOBAL_AS __attribute__((address_space(1)))
#define LDS_AS    __attribute__((address_space(3)))

typedef _Float16 f16;
typedef _Float16 half8 __attribute__((ext_vector_type(8)));
typedef float    f32x4 __attribute__((ext_vector_type(4)));

constexpr int B_  = 16;
constexpr int T_  = 2048;
constexpr int IN_ = 65;
constexpr int HID = 64;
constexpr int G4  = 256;      // 4*HID
constexpr int FW  = 72;       // padded frame width (25*72 = 1800)
constexpr int KP  = 1824;     // padded K for layer0 (57*32)
constexpr int KC0 = KP / 32;  // 57

// ---- workspace layout (bytes) ----
constexpr size_t OFF_XF   = 0;                          // [B][T][FW] f16
constexpr size_t SZ_XF    = (size_t)B_ * T_ * FW * 2;   // 4,718,592
constexpr size_t OFF_WP0  = OFF_XF + SZ_XF;             // [KC0][16][64][8] f16
constexpr size_t SZ_WP0   = (size_t)KC0 * 16 * 64 * 8 * 2;
constexpr size_t OFF_WHHF = OFF_WP0 + SZ_WP0;           // 3 x r-layout frags
constexpr size_t SZ_WHHF1 = (size_t)16 * 2 * 64 * 8 * 2;
constexpr size_t OFF_WIHR = OFF_WHHF + 3 * SZ_WHHF1;    // 2 x r-layout frags (Wih1, Wih2)
constexpr size_t SZ_WIHR1 = (size_t)16 * 2 * 64 * 8 * 2;
constexpr size_t OFF_BC   = OFF_WIHR + 2 * SZ_WIHR1;    // 3 x [256] f32
constexpr size_t OFF_PRE  = ((OFF_BC + 3 * 256 * 4 + 1023) / 1024) * 1024;  // [t][b][j][q] f32, layer 0 only
constexpr size_t SZ_PRE   = (size_t)T_ * B_ * G4 * 4;   // 33,554,432
constexpr size_t OFF_H2   = OFF_PRE + SZ_PRE;           // [B][T][HID] f16 (final layer h only)
constexpr size_t SZ_H     = (size_t)B_ * T_ * HID * 2;  // 4,194,304

__device__ __forceinline__ void async_copy16(const void* g, void* l) {
  __builtin_amdgcn_global_load_lds((const GLOBAL_AS void*)g, (LDS_AS void*)l, 16, 0, 0);
}

// within-row byte offset for pre[t][b][g] (plain): g=(q*64+j) -> j*16 + q*4
__device__ __forceinline__ int pre_col_byte(int g) {
  int j = g & 63, q = g >> 6;
  return (j << 4) | (q << 2);
}

__device__ __forceinline__ float fsig(float x) {
  return __builtin_amdgcn_rcpf(1.f + __builtin_amdgcn_exp2f(-1.4426950408889634f * x));
}
__device__ __forceinline__ float ftanh(float x) {
  return 1.f - 2.f * __builtin_amdgcn_rcpf(1.f + __builtin_amdgcn_exp2f(2.8853900817779268f * x));
}

// PIN: identity asm makes the value's origin opaque -> the register allocator
// CANNOT rematerialize the originating (const __restrict__) load inside the
// t-loop; the fragment must stay resident in VGPRs. (r6 post-mortem: VGPR=104
// with ~210 needed => compiler was re-loading weight frags from L2 every step.)
__device__ __forceinline__ void pin(half8& v)  { asm("" : "+v"(v)); }
__device__ __forceinline__ void pinf(float& v) { asm("" : "+v"(v)); }

// ================= pack kernel =================
__global__ void pack_kernel(const float* __restrict__ in0, const float* __restrict__ Wih0,
                            const float* __restrict__ Whh0, const float* __restrict__ bih0, const float* __restrict__ bhh0,
                            const float* __restrict__ Wih1, const float* __restrict__ Whh1, const float* __restrict__ bih1, const float* __restrict__ bhh1,
                            const float* __restrict__ Wih2, const float* __restrict__ Whh2, const float* __restrict__ bih2, const float* __restrict__ bhh2,
                            f16* __restrict__ xf, f16* __restrict__ wp0,
                            f16* __restrict__ whhf, f16* __restrict__ wihr, float* __restrict__ bc)
{
  const int stride = gridDim.x * blockDim.x;
  const int tid0 = blockIdx.x * blockDim.x + threadIdx.x;

  // xf: [B][T][FW], zero-pad f >= 65
  const int NX = B_ * T_ * FW;
  for (int i = tid0; i < NX; i += stride) {
    int f = i % FW; int bt = i / FW;
    float v = (f < IN_) ? in0[(size_t)bt * IN_ + f] : 0.f;
    xf[i] = (f16)v;
  }
  // wp0: [kc][nt][lane][8] ; k' = kc*32 + (l>>4)*8 + j ; g = nt*16 + (l&15)
  const int NW0 = KC0 * 16 * 64 * 8;
  for (int i = tid0; i < NW0; i += stride) {
    int j = i & 7, l = (i >> 3) & 63, nt = (i >> 9) & 15, kc = i >> 13;
    int kp = kc * 32 + ((l >> 4) * 8 + j);
    int g  = nt * 16 + (l & 15);
    int d = kp / FW, f = kp % FW;
    float v = (kp < 1800 && f < IN_) ? Wih0[(size_t)g * 1625 + d * IN_ + f] : 0.f;
    wp0[i] = (f16)v;
  }
  // whhf (r-layout): per layer, frag tt = jb*4+u, kf:
  //   g = u*64 + jb*16 + (l&15) ; k = kf*32 + (l>>4)*8 + e
  const float* whhs[3] = {Whh0, Whh1, Whh2};
  for (int i = tid0; i < 3 * 16384; i += stride) {
    int L = i >> 14, r = i & 16383;
    int e = r & 7, l = (r >> 3) & 63, kf = (r >> 9) & 1, tt = (r >> 10) & 15;
    int jb = tt >> 2, u = tt & 3;
    int g = u * 64 + jb * 16 + (l & 15);
    int k = kf * 32 + ((l >> 4) * 8) + e;
    whhf[i] = (f16)whhs[L][g * 64 + k];
  }
  // wihr (r-layout, same formula) from Wih1/Wih2 (both [256][64])
  const float* wihs[2] = {Wih1, Wih2};
  for (int i = tid0; i < 2 * 16384; i += stride) {
    int L = i >> 14, r = i & 16383;
    int e = r & 7, l = (r >> 3) & 63, kf = (r >> 9) & 1, tt = (r >> 10) & 15;
    int jb = tt >> 2, u = tt & 3;
    int g = u * 64 + jb * 16 + (l & 15);
    int k = kf * 32 + ((l >> 4) * 8) + e;
    wihr[i] = (f16)wihs[L][g * 64 + k];
  }
  // combined biases
  const float* bis[3] = {bih0, bih1, bih2};
  const float* bhs[3] = {bhh0, bhh1, bhh2};
  for (int i = tid0; i < 3 * 256; i += stride) {
    int L = i >> 8, g = i & 255;
    bc[i] = bis[L][g] + bhs[L][g];
  }
}

// ================= layer-0 windowed GEMM =================
// grid (32, 16): x = t-tile (64 rows), y = batch. 256 threads = 4 waves.
__global__ __launch_bounds__(256) void gemm0_kernel(const f16* __restrict__ xf, const f16* __restrict__ wp0,
                                                    const float* __restrict__ bc0, float* __restrict__ pre)
{
  __shared__ __align__(16) f16 frames[90 * FW];   // 12,960 B
  __shared__ __align__(16) f16 bbuf[16 * 64 * 8]; // 16,384 B
  const int tid = threadIdx.x, l = tid & 63, w = tid >> 6;
  const int b = blockIdx.y, t0 = blockIdx.x * 64;

  // zero frames (covers t-edge padding and the k'>=1800 tail rows)
  for (int c = tid; c < 810; c += 256) *(f32x4*)(&frames[c * 8]) = (f32x4)0.f;
  __syncthreads();

  // stage valid frame range [s0, s1) of this batch
  {
    const int st = t0 - 12;
    const int s0 = st < 0 ? 0 : st;
    const int s1 = (t0 + 78) < T_ ? (t0 + 78) : T_;
    const int dstrow = s0 - st;
    const int nchunk = (s1 - s0) * 9;  // 16B chunks (144 B/row)
    const f16* gsrc = xf + ((size_t)b * T_ + s0) * FW;
    for (int base = 0; base < 810; base += 256) {
      int idx = base + w * 64 + l;
      if (idx < nchunk) {
        char* ldsb = (char*)frames + dstrow * 144 + (base + w * 64) * 16;
        async_copy16((const char*)gsrc + (size_t)(base + w * 64) * 16 + l * 16, ldsb);
      }
    }
  }

  f32x4 acc[16];
#pragma unroll
  for (int i = 0; i < 16; ++i) acc[i] = (f32x4)0.f;

  for (int kc = 0; kc < KC0; ++kc) {
    __syncthreads();  // drains previous loads/reads; protects bbuf
    const f16* wsrc = wp0 + (size_t)kc * 8192;
#pragma unroll
    for (int i = 0; i < 4; ++i) {
      char* ldsb = (char*)bbuf + (i * 256 + w * 64) * 16;
      async_copy16((const char*)wsrc + (size_t)(i * 256 + w * 64 + l) * 16, ldsb);
    }
    __syncthreads();  // vmcnt(0) drain -> bbuf ready

    int kp0 = kc * 32 + ((l >> 4) * 8);
    int d = kp0 / FW, f = kp0 % FW;
    int r = w * 16 + (l & 15);
    half8 af = *(const half8*)(&frames[(r + d) * FW + f]);
#pragma unroll
    for (int nt = 0; nt < 16; ++nt) {
      half8 bf = *(const half8*)(&bbuf[(nt * 64 + l) * 8]);
      acc[nt] = __builtin_amdgcn_mfma_f32_16x16x32_f16(af, bf, acc[nt], 0, 0, 0);
    }
  }

  // epilogue: bias + plain [t][b][j][q] store
  const int n_ = l & 15, grp = l >> 4;
#pragma unroll
  for (int nt = 0; nt < 16; ++nt) {
    int g = nt * 16 + n_;
    float bias = bc0[g];
    int colByte = pre_col_byte(g);
#pragma unroll
    for (int rr = 0; rr < 4; ++rr) {
      int t = t0 + w * 16 + grp * 4 + rr;
      *(float*)((char*)pre + (size_t)t * 16384 + (size_t)b * 1024 + colByte) = acc[nt][rr] + bias;
    }
  }
}

// ================= fused 3-layer LSTM recurrence, 8 blocks x 6 waves =================
// Block handles 2 batches; wave w: layer L=w>>1, half wv=w&1. Lane (grp,n):
// batch b_loc=grp>>1, j=(2wv+(grp&1))*16+n. A replicated 8x (16 rows = 2b x 8);
// per wave 8 N-tiles (jb in {2wv,2wv+1} x u), lane picks its jb-acc with one
// cndmask per gate. ONE barrier/step, parity-selected LDS pointers, depth-3
// register pre-ring for L0, Wih folded into MFMAs for L1/L2. Weight frags and
// biases PINNED in VGPRs (see pin()).
__global__ __launch_bounds__(384, 2) void r6_kernel(const float* __restrict__ pre,
                                                    const f16* __restrict__ whhf,
                                                    const f16* __restrict__ wihr,
                                                    const float* __restrict__ bc,
                                                    f16* __restrict__ h2out)
{
  __shared__ __align__(16) char hring[6 * 256];   // [layer][slot][b_loc][64 k] f16
  const int tid = threadIdx.x, l = tid & 63, w = tid >> 6;
  const int L = w >> 1, wv = w & 1;
  const int n_ = l & 15, grp = l >> 4;
  const int jb_own = wv * 2 + (grp & 1);
  const int j  = jb_own * 16 + n_;   // hidden index this lane updates
  const int b_loc = grp >> 1;        // local batch this lane updates
  const int bglob = blockIdx.x * 2 + b_loc;
  const int arow = n_ >> 3;          // A-frag source batch (row n_, batch n_>>3)
  const bool selB = (grp & 1) != 0;  // lane uses jb = 2wv+1 accs

  // recurrent (Whh) fragments: tiles (jb = 2wv+ji, u), kf  -- PINNED
  half8 bfh[2][4][2];
  const f16* wh = whhf + (size_t)L * 16384;
#pragma unroll
  for (int ji = 0; ji < 2; ++ji)
#pragma unroll
    for (int u = 0; u < 4; ++u)
#pragma unroll
      for (int kf = 0; kf < 2; ++kf) {
        int tt = (wv * 2 + ji) * 4 + u;
        bfh[ji][u][kf] = *(const half8*)(wh + (((tt * 2) + kf) << 9) + (l << 3));
        pin(bfh[ji][u][kf]);
      }

  // input (Wih) fragments for layers 1,2 -- PINNED
  half8 bfx[2][4][2];
  if (L > 0) {
    const f16* wx = wihr + (size_t)(L - 1) * 16384;
#pragma unroll
    for (int ji = 0; ji < 2; ++ji)
#pragma unroll
      for (int u = 0; u < 4; ++u)
#pragma unroll
        for (int kf = 0; kf < 2; ++kf) {
          int tt = (wv * 2 + ji) * 4 + u;
          bfx[ji][u][kf] = *(const half8*)(wx + (((tt * 2) + kf) << 9) + (l << 3));
          pin(bfx[ji][u][kf]);
        }
  }

  float bi[4] = {0.f, 0.f, 0.f, 0.f};
  if (L > 0) {
#pragma unroll
    for (int u = 0; u < 4; ++u) { bi[u] = bc[L * 256 + u * 64 + j]; pinf(bi[u]); }
  }

  // zero h rings (1536 B)
  if (tid < 96) *(f32x4*)(hring + tid * 16) = (f32x4)0.f;
  float c = 0.f;

  // parity-selected LDS pointers (t&1 = sp ^ (L&1))
  const int lp = L & 1;
  const int Lm1 = (L > 0) ? (L - 1) : 0;
  const char* ownRd0 = hring + (L * 2 + (1 ^ lp)) * 256 + arow * 128 + grp * 16;   // sp=0: slot (t-1)&1
  const char* ownRd1 = hring + (L * 2 + (0 ^ lp)) * 256 + arow * 128 + grp * 16;   // sp=1
  const char* inRd0  = hring + (Lm1 * 2 + (0 ^ lp)) * 256 + arow * 128 + grp * 16; // sp=0: slot t&1
  const char* inRd1  = hring + (Lm1 * 2 + (1 ^ lp)) * 256 + arow * 128 + grp * 16; // sp=1
  char* wr0 = hring + (L * 2 + (0 ^ lp)) * 256 + b_loc * 128 + j * 2;              // sp=0: slot t&1
  char* wr1 = hring + (L * 2 + (1 ^ lp)) * 256 + b_loc * 128 + j * 2;              // sp=1

  // register pre ring (L0 only), depth 3
  f32x4 P0 = (f32x4)0.f, P1 = (f32x4)0.f, P2 = (f32x4)0.f, P3 = (f32x4)0.f;
  const GLOBAL_AS char* preP =
      (const GLOBAL_AS char*)(uintptr_t)((const char*)pre + (size_t)bglob * 1024 + (size_t)j * 16);
  if (L == 0) {
    P0 = *(const GLOBAL_AS f32x4*)(preP);
    P1 = *(const GLOBAL_AS f32x4*)(preP + 16384);
    P2 = *(const GLOBAL_AS f32x4*)(preP + 32768);
    preP += 3 * 16384;
  }
  GLOBAL_AS f16* h2p = (GLOBAL_AS f16*)(uintptr_t)(h2out + (size_t)bglob * T_ * HID + j);

#define R6STEP(S_, PU_, PLD_, SP_)                                                             \
  {                                                                                            \
    asm volatile("s_waitcnt lgkmcnt(0)" ::: "memory");                                         \
    __builtin_amdgcn_s_barrier();                                                              \
    __builtin_amdgcn_sched_barrier(0);                                                         \
    const int t = (S_) - L;                                                                    \
    const bool act = (unsigned)t < (unsigned)T_;                                               \
    if (L == 0 && (t + 3) < T_) {                                                              \
      PLD_ = *(const GLOBAL_AS f32x4*)(preP);                                                  \
      preP += 16384;                                                                           \
    }                                                                                          \
    if (act) {                                                                                 \
      const char* Hc = (SP_) ? ownRd1 : ownRd0;                                                \
      half8 a0 = *(const half8*)(Hc);                                                          \
      half8 a1 = *(const half8*)(Hc + 64);                                                     \
      f32x4 aA[4], aB[4];                                                                      \
      if (L > 0) {                                                                             \
        const char* Xc = (SP_) ? inRd1 : inRd0;                                                \
        half8 x0 = *(const half8*)(Xc);                                                        \
        half8 x1 = *(const half8*)(Xc + 64);                                                   \
        _Pragma("unroll")                                                                      \
        for (int u = 0; u < 4; ++u) {                                                          \
          aA[u] = __builtin_amdgcn_mfma_f32_16x16x32_f16(x0, bfx[0][u][0], (f32x4)0.f, 0, 0, 0); \
          aA[u] = __builtin_amdgcn_mfma_f32_16x16x32_f16(x1, bfx[0][u][1], aA[u], 0, 0, 0);    \
          aA[u] = __builtin_amdgcn_mfma_f32_16x16x32_f16(a0, bfh[0][u][0], aA[u], 0, 0, 0);    \
          aA[u] = __builtin_amdgcn_mfma_f32_16x16x32_f16(a1, bfh[0][u][1], aA[u], 0, 0, 0);    \
          aB[u] = __builtin_amdgcn_mfma_f32_16x16x32_f16(x0, bfx[1][u][0], (f32x4)0.f, 0, 0, 0); \
          aB[u] = __builtin_amdgcn_mfma_f32_16x16x32_f16(x1, bfx[1][u][1], aB[u], 0, 0, 0);    \
          aB[u] = __builtin_amdgcn_mfma_f32_16x16x32_f16(a0, bfh[1][u][0], aB[u], 0, 0, 0);    \
          aB[u] = __builtin_amdgcn_mfma_f32_16x16x32_f16(a1, bfh[1][u][1], aB[u], 0, 0, 0);    \
        }                                                                                      \
      } else {                                                                                 \
        _Pragma("unroll")                                                                      \
        for (int u = 0; u < 4; ++u) {                                                          \
          aA[u] = __builtin_amdgcn_mfma_f32_16x16x32_f16(a0, bfh[0][u][0], (f32x4)0.f, 0, 0, 0); \
          aA[u] = __builtin_amdgcn_mfma_f32_16x16x32_f16(a1, bfh[0][u][1], aA[u], 0, 0, 0);    \
          aB[u] = __builtin_amdgcn_mfma_f32_16x16x32_f16(a0, bfh[1][u][0], (f32x4)0.f, 0, 0, 0); \
          aB[u] = __builtin_amdgcn_mfma_f32_16x16x32_f16(a1, bfh[1][u][1], aB[u], 0, 0, 0);    \
        }                                                                                      \
      }                                                                                        \
      float g0 = selB ? aB[0][0] : aA[0][0];                                                   \
      float g1 = selB ? aB[1][0] : aA[1][0];                                                   \
      float g2 = selB ? aB[2][0] : aA[2][0];                                                   \
      float g3 = selB ? aB[3][0] : aA[3][0];                                                   \
      float iv, fv, gv, ov;                                                                    \
      if (L == 0) {                                                                            \
        iv = g0 + PU_.x; fv = g1 + PU_.y; gv = g2 + PU_.z; ov = g3 + PU_.w;                    \
      } else {                                                                                 \
        iv = g0 + bi[0]; fv = g1 + bi[1]; gv = g2 + bi[2]; ov = g3 + bi[3];                    \
      }                                                                                        \
      c = fsig(fv) * c + fsig(iv) * ftanh(gv);                                                 \
      float hv = fsig(ov) * ftanh(c);                                                          \
      f16 h16v = (f16)hv;                                                                      \
      *(f16*)((SP_) ? wr1 : wr0) = h16v;                                                       \
      if (L == 2) { *h2p = h16v; h2p += HID; }                                                 \
    }                                                                                          \
  }

  // steps s = 0 .. 2051 (covers t up to 2047 for L=2 at s=2049)
  for (int s4 = 0; s4 < T_ + 4; s4 += 4) {
    R6STEP(s4 + 0, P0, P3, 0)
    R6STEP(s4 + 1, P1, P0, 1)
    R6STEP(s4 + 2, P2, P1, 0)
    R6STEP(s4 + 3, P3, P2, 1)
  }
#undef R6STEP
}

// ================= final projection =================
__global__ __launch_bounds__(256) void fin_kernel(const f16* __restrict__ h2, const float* __restrict__ Wout,
                                                  const float* __restrict__ bout, float* __restrict__ out)
{
  __shared__ float wl[64];
  const int tid = threadIdx.x;
  if (tid < 64) wl[tid] = Wout[tid];
  __syncthreads();
  const int idx = blockIdx.x * 256 + tid;  // = b*T + t
  const f16* hr = h2 + (size_t)idx * HID;
  float acc = bout[0];
#pragma unroll
  for (int i = 0; i < 64; i += 8) {
    half8 hv = *(const half8*)(hr + i);
#pragma unroll
    for (int k = 0; k < 8; ++k) {
      float h = (float)hv[k];
      h = fmaxf(h, 0.f);
      acc += h * wl[i + k];
    }
  }
  out[idx] = fsig(acc);
}

// ================= launcher =================
extern "C" void kernel_launch(void* const* d_in, const int* in_sizes, int n_in,
                              void* d_out, int out_size, void* d_ws, size_t ws_size,
                              hipStream_t stream)
{
  (void)in_sizes; (void)n_in; (void)out_size; (void)ws_size;
  const float* in0  = (const float*)d_in[0];
  const float* Wih0 = (const float*)d_in[1];
  const float* Whh0 = (const float*)d_in[2];
  const float* bih0 = (const float*)d_in[3];
  const float* bhh0 = (const float*)d_in[4];
  const float* Wih1 = (const float*)d_in[5];
  const float* Whh1 = (const float*)d_in[6];
  const float* bih1 = (const float*)d_in[7];
  const float* bhh1 = (const float*)d_in[8];
  const float* Wih2 = (const float*)d_in[9];
  const float* Whh2 = (const float*)d_in[10];
  const float* bih2 = (const float*)d_in[11];
  const float* bhh2 = (const float*)d_in[12];
  const float* Wout = (const float*)d_in[13];
  const float* bout = (const float*)d_in[14];
  float* out = (float*)d_out;

  char* ws = (char*)d_ws;
  f16*   xf   = (f16*)(ws + OFF_XF);
  f16*   wp0  = (f16*)(ws + OFF_WP0);
  f16*   whhf = (f16*)(ws + OFF_WHHF);
  f16*   wihr = (f16*)(ws + OFF_WIHR);
  float* bc   = (float*)(ws + OFF_BC);
  float* pre  = (float*)(ws + OFF_PRE);
  f16*   h2   = (f16*)(ws + OFF_H2);

  pack_kernel<<<256, 256, 0, stream>>>(in0, Wih0, Whh0, bih0, bhh0,
                                       Wih1, Whh1, bih1, bhh1,
                                       Wih2, Whh2, bih2, bhh2,
                                       xf, wp0, whhf, wihr, bc);
  gemm0_kernel<<<dim3(32, 16), 256, 0, stream>>>(xf, wp0, bc, pre);
  r6_kernel<<<8, 384, 0, stream>>>(pre, whhf, wihr, bc, h2);
  fin_kernel<<<128, 256, 0, stream>>>(h2, Wout, bout, out);
}